// Round 4
// baseline (197.859 us; speedup 1.0000x reference)
//
#include <hip/hip_runtime.h>

// VQ quantizer: z [8,8,16,64,64] f32, codebook [512,8] f32
// outputs concat: z_q_st (4194304 f32) | vq_loss (1 f32) | idx (524288 f32-valued)
//
// R4: forced v_pk_fma_f32/v_pk_add_f32 (inline asm), LDS-staged pair records,
// pair-id-only argmin tracking with exact scalar epilogue resolution.
// Each pk half = independent IEEE fp32 op -> np-bit-exact (R1-R3: absmax 0).

#define NPTS      524288      // 8*16*64*64
#define KCODES    512
#define NPAIRS    256
#define DDIM      8
#define CH_STRIDE 65536       // T*H*W
#define B_STRIDE  524288      // D*T*H*W
#define PPT       2           // points per thread
#define BLK       256
#define RECF      20          // floats per pair record (80B = 5 float4)
#define FLT_BIG   3.402823466e+38f

typedef float v2f __attribute__((ext_vector_type(2)));

__device__ __forceinline__ v2f pk_fma(v2f a, v2f b, v2f c) {
    v2f d;
    asm("v_pk_fma_f32 %0, %1, %2, %3" : "=v"(d) : "v"(a), "v"(b), "v"(c));
    return d;
}
__device__ __forceinline__ v2f pk_add(v2f a, v2f b) {
    v2f d;
    asm("v_pk_add_f32 %0, %1, %2" : "=v"(d) : "v"(a), "v"(b));
    return d;
}

// numpy pairwise-sum tree for n=8: ((x0+x1)+(x2+x3)) + ((x4+x5)+(x6+x7)),
// products rounded separately (no fma).
__device__ __forceinline__ float np_sumsq8(const float* x) {
    float p0 = __fmul_rn(x[0], x[0]);
    float p1 = __fmul_rn(x[1], x[1]);
    float p2 = __fmul_rn(x[2], x[2]);
    float p3 = __fmul_rn(x[3], x[3]);
    float p4 = __fmul_rn(x[4], x[4]);
    float p5 = __fmul_rn(x[5], x[5]);
    float p6 = __fmul_rn(x[6], x[6]);
    float p7 = __fmul_rn(x[7], x[7]);
    return __fadd_rn(__fadd_rn(__fadd_rn(p0, p1), __fadd_rn(p2, p3)),
                     __fadd_rn(__fadd_rn(p4, p5), __fadd_rn(p6, p7)));
}

// Pair records: rec g = codes (2g,2g+1) interleaved [c0a c0b ... c7a c7b] + e2a e2b + pad2.
__global__ void prep_pairs(const float* __restrict__ cb, float* __restrict__ pk) {
    int g = threadIdx.x;  // 256 threads, 1 block
    if (g >= NPAIRS) return;
    float a[DDIM], b[DDIM];
    #pragma unroll
    for (int j = 0; j < DDIM; ++j) {
        a[j] = cb[(2 * g) * DDIM + j];
        b[j] = cb[(2 * g + 1) * DDIM + j];
    }
    float* r = pk + (size_t)g * RECF;
    #pragma unroll
    for (int j = 0; j < DDIM; ++j) { r[2 * j] = a[j]; r[2 * j + 1] = b[j]; }
    r[16] = np_sumsq8(a);
    r[17] = np_sumsq8(b);
    r[18] = 0.0f; r[19] = 0.0f;
}

// distances for pair g against both points; update per-point (dm, g*) with strict <.
__device__ __forceinline__ void process_pair(
    const float4 r[5], const v2f zd0[DDIM], const v2f zd1[DDIM],
    v2f z2d0, v2f z2d1, v2f m2, int gidx,
    float& dm0, int& g0, float& dm1, int& g1)
{
    v2f cp[DDIM];
    cp[0] = (v2f){r[0].x, r[0].y}; cp[1] = (v2f){r[0].z, r[0].w};
    cp[2] = (v2f){r[1].x, r[1].y}; cp[3] = (v2f){r[1].z, r[1].w};
    cp[4] = (v2f){r[2].x, r[2].y}; cp[5] = (v2f){r[2].z, r[2].w};
    cp[6] = (v2f){r[3].x, r[3].y}; cp[7] = (v2f){r[3].z, r[3].w};
    const v2f e2p = (v2f){r[4].x, r[4].y};

    // np (OpenBLAS) sequential ascending-j fma chain from 0, per half
    v2f ze0 = (v2f){0.0f, 0.0f};
    v2f ze1 = (v2f){0.0f, 0.0f};
    #pragma unroll
    for (int j = 0; j < DDIM; ++j) {
        ze0 = pk_fma(zd0[j], cp[j], ze0);
        ze1 = pk_fma(zd1[j], cp[j], ze1);
    }
    const v2f t0 = pk_add(z2d0, e2p);          // np: z2 + e2
    const v2f t1 = pk_add(z2d1, e2p);
    const v2f d0 = pk_fma(m2, ze0, t0);        // np: t - 2*ze (2*ze exact)
    const v2f d1 = pk_fma(m2, ze1, t1);

    const float v0 = fminf(d0.x, d0.y);
    const float v1 = fminf(d1.x, d1.y);
    // strict <: first pair reaching a new min wins (np first-min across pairs)
    if (v0 < dm0) { g0 = gidx; dm0 = v0; }
    if (v1 < dm1) { g1 = gidx; dm1 = v1; }
}

// exact within-pair resolution: recompute both dists scalar (bit-identical to pk
// halves), odd wins only if strictly less (np scan order even-then-odd).
__device__ __forceinline__ int resolve_pair(const float* lds_pk, int g,
                                            const v2f zd[DDIM], float z2) {
    const float* r = lds_pk + (size_t)g * RECF;
    float zee = 0.0f, zeo = 0.0f;
    #pragma unroll
    for (int j = 0; j < DDIM; ++j) {
        zee = __fmaf_rn(zd[j].x, r[2 * j],     zee);
        zeo = __fmaf_rn(zd[j].x, r[2 * j + 1], zeo);
    }
    const float de = __fmaf_rn(-2.0f, zee, __fadd_rn(z2, r[16]));
    const float dq = __fmaf_rn(-2.0f, zeo, __fadd_rn(z2, r[17]));
    return (dq < de) ? (2 * g + 1) : (2 * g);
}

__global__ __launch_bounds__(BLK, 4) void vq_main(
    const float* __restrict__ z, const float* __restrict__ pk,
    float* __restrict__ out_zq, float* __restrict__ out_loss,
    float* __restrict__ out_idx)
{
    __shared__ float lds_pk[NPAIRS * RECF];   // 20 KB

    // stage records global -> LDS, coalesced float4
    {
        const float4* gsrc = (const float4*)pk;
        float4* ldst = (float4*)lds_pk;
        #pragma unroll
        for (int q = 0; q < 5; ++q)
            ldst[threadIdx.x + q * BLK] = gsrc[threadIdx.x + q * BLK];
    }

    const int base = blockIdx.x * (BLK * PPT) + threadIdx.x;

    // load P=2 points; duplicate z into both pk halves (loop-invariant)
    v2f zd[PPT][DDIM];
    v2f z2d[PPT];
    float z2s[PPT];
    #pragma unroll
    for (int p = 0; p < PPT; ++p) {
        const int n = base + p * BLK;
        const int b = n >> 16;
        const int s = n & 65535;
        const float* zp = z + (size_t)b * B_STRIDE + s;
        float tmp[DDIM];
        #pragma unroll
        for (int j = 0; j < DDIM; ++j) {
            tmp[j] = zp[(size_t)j * CH_STRIDE];
            zd[p][j] = (v2f){tmp[j], tmp[j]};
        }
        z2s[p] = np_sumsq8(tmp);
        z2d[p] = (v2f){z2s[p], z2s[p]};
    }

    __syncthreads();

    const v2f m2 = (v2f){-2.0f, -2.0f};
    float dm0 = FLT_BIG, dm1 = FLT_BIG;
    int g0 = 0, g1 = 0;

    const float4* lrec = (const float4*)lds_pk;   // 5 float4 per record
    float4 ra[5], rb[5];
    #pragma unroll
    for (int q = 0; q < 5; ++q) { ra[q] = lrec[q]; rb[q] = lrec[5 + q]; }

    for (int it = 0; it < NPAIRS / 2; ++it) {
        const int gA = 2 * it, gB = 2 * it + 1;

        process_pair(ra, zd[0], zd[1], z2d[0], z2d[1], m2, gA, dm0, g0, dm1, g1);
        // refill ra with pair gA+2 (write-after-use, no copies; wrap harmless)
        {
            const int nA = (gA + 2) & (NPAIRS - 1);
            #pragma unroll
            for (int q = 0; q < 5; ++q) ra[q] = lrec[nA * 5 + q];
        }

        process_pair(rb, zd[0], zd[1], z2d[0], z2d[1], m2, gB, dm0, g0, dm1, g1);
        {
            const int nB = (gB + 2) & (NPAIRS - 1);
            #pragma unroll
            for (int q = 0; q < 5; ++q) rb[q] = lrec[nB * 5 + q];
        }
    }

    const int gm[PPT] = {g0, g1};
    float lsum = 0.0f;
    #pragma unroll
    for (int p = 0; p < PPT; ++p) {
        const int n = base + p * BLK;
        const int b = n >> 16;
        const int s = n & 65535;
        const int idx = resolve_pair(lds_pk, gm[p], zd[p], z2s[p]);
        const float* cw = lds_pk + (size_t)(idx >> 1) * RECF + (idx & 1);
        float* op = out_zq + (size_t)b * B_STRIDE + s;
        #pragma unroll
        for (int j = 0; j < DDIM; ++j) {
            const float zq  = cw[2 * j];
            const float zvj = zd[p][j].x;
            const float t   = __fsub_rn(zq, zvj);            // np: z_q - z
            op[(size_t)j * CH_STRIDE] = __fadd_rn(zvj, t);   // np: z + (z_q - z)
            lsum = __fmaf_rn(t, t, lsum);                    // loss (2% tol)
        }
        out_idx[n] = (float)idx;
    }

    // block reduction of loss partials: wave shuffle -> LDS -> one atomic/block
    #pragma unroll
    for (int off = 32; off > 0; off >>= 1) lsum += __shfl_down(lsum, off, 64);
    __shared__ float wsum[4];
    const int lane = threadIdx.x & 63;
    const int wid  = threadIdx.x >> 6;
    if (lane == 0) wsum[wid] = lsum;
    __syncthreads();
    if (threadIdx.x == 0) {
        float bs = ((wsum[0] + wsum[1]) + (wsum[2] + wsum[3]));
        // vq_loss = codebk + BETA*commit = 1.25 * mean((z_q - z)^2)
        atomicAdd(out_loss, bs * (1.25f / 4194304.0f));
    }
}

extern "C" void kernel_launch(void* const* d_in, const int* in_sizes, int n_in,
                              void* d_out, int out_size, void* d_ws, size_t ws_size,
                              hipStream_t stream) {
    const float* z  = (const float*)d_in[0];
    const float* cb = (const float*)d_in[1];
    float* out      = (float*)d_out;
    float* out_zq   = out;                    // 4194304 elems
    float* out_loss = out + 4194304;          // 1 elem
    float* out_idx  = out + 4194305;          // 524288 elems (as float values)
    float* pk       = (float*)d_ws;           // 256 pair-records * 20 floats

    hipMemsetAsync(out_loss, 0, sizeof(float), stream);
    prep_pairs<<<1, 256, 0, stream>>>(cb, pk);
    vq_main<<<NPTS / (BLK * PPT), BLK, 0, stream>>>(z, pk, out_zq, out_loss, out_idx);
}

// Round 5
// 165.160 us; speedup vs baseline: 1.1980x; 1.1980x over previous
//
#include <hip/hip_runtime.h>

// VQ quantizer: z [8,8,16,64,64] f32, codebook [512,8] f32
// outputs concat: z_q_st (4194304 f32) | vq_loss (1 f32) | idx (524288 f32-valued)
//
// R5: back to P=1 simple shape (R1-like, 85% busy) with the overhead removed:
// - pair loop reads raw codebook via uniform float4 loads (no packing, no arrays)
// - e2 from a tiny prep table (float2 per pair)
// - 24 VALU/pair argmin (track pair-id only; exact within-pair resolve in epilogue,
//   pattern correctness-validated in R4: absmax 0)
// - named scalars/float4 temporaries only -> no alloca/scratch (R2-R4 lesson:
//   VGPR_Count below nominal live state == spilled arrays == 2x inst bloat)

#define NPTS      524288      // 8*16*64*64
#define KCODES    512
#define NPAIRS    256
#define DDIM      8
#define CH_STRIDE 65536       // T*H*W
#define B_STRIDE  524288      // D*T*H*W
#define BLK       256
#define FLT_BIG   3.402823466e+38f

// numpy pairwise-sum tree for n=8: ((x0+x1)+(x2+x3)) + ((x4+x5)+(x6+x7)),
// products rounded separately (no fma).
__device__ __forceinline__ float np_sumsq8(const float* x) {
    float p0 = __fmul_rn(x[0], x[0]);
    float p1 = __fmul_rn(x[1], x[1]);
    float p2 = __fmul_rn(x[2], x[2]);
    float p3 = __fmul_rn(x[3], x[3]);
    float p4 = __fmul_rn(x[4], x[4]);
    float p5 = __fmul_rn(x[5], x[5]);
    float p6 = __fmul_rn(x[6], x[6]);
    float p7 = __fmul_rn(x[7], x[7]);
    return __fadd_rn(__fadd_rn(__fadd_rn(p0, p1), __fadd_rn(p2, p3)),
                     __fadd_rn(__fadd_rn(p4, p5), __fadd_rn(p6, p7)));
}

// e2[k] = np-exact sum of squares of code k; thread 0 also zeroes the loss cell
// (prep runs before vq_main in stream order -> all atomics land after the zero).
__global__ void prep_e2(const float* __restrict__ cb, float* __restrict__ e2,
                        float* __restrict__ out_loss) {
    int k = threadIdx.x;  // 512 threads, 1 block
    if (k == 0) *out_loss = 0.0f;
    if (k >= KCODES) return;
    float c[DDIM];
    #pragma unroll
    for (int j = 0; j < DDIM; ++j) c[j] = cb[k * DDIM + j];
    e2[k] = np_sumsq8(c);
}

__global__ __launch_bounds__(BLK, 8) void vq_main(
    const float* __restrict__ z, const float* __restrict__ cb,
    const float* __restrict__ e2tab, float* __restrict__ out_zq,
    float* __restrict__ out_loss, float* __restrict__ out_idx)
{
    const int n = blockIdx.x * BLK + threadIdx.x;
    const int b = n >> 16;
    const int s = n & 65535;
    const float* zp = z + (size_t)b * B_STRIDE + s;

    float zv[DDIM];
    #pragma unroll
    for (int j = 0; j < DDIM; ++j) zv[j] = zp[(size_t)j * CH_STRIDE];
    const float z2 = np_sumsq8(zv);

    float dm = FLT_BIG;
    int gbest = 0;

    const float4* cb4 = (const float4*)cb;      // 2 float4 per code
    const float2* e2p = (const float2*)e2tab;   // 1 float2 per pair

    #pragma unroll 2
    for (int g = 0; g < NPAIRS; ++g) {
        // pair g = codes (2g, 2g+1): 4 uniform float4 loads + 1 float2 load
        const float4 a0 = cb4[4 * g + 0];
        const float4 a1 = cb4[4 * g + 1];
        const float4 b0 = cb4[4 * g + 2];
        const float4 b1 = cb4[4 * g + 3];
        const float2 ee = e2p[g];

        // np (OpenBLAS) sequential ascending-j fma chain from 0
        float zea = 0.0f, zeb = 0.0f;
        zea = __fmaf_rn(zv[0], a0.x, zea);  zeb = __fmaf_rn(zv[0], b0.x, zeb);
        zea = __fmaf_rn(zv[1], a0.y, zea);  zeb = __fmaf_rn(zv[1], b0.y, zeb);
        zea = __fmaf_rn(zv[2], a0.z, zea);  zeb = __fmaf_rn(zv[2], b0.z, zeb);
        zea = __fmaf_rn(zv[3], a0.w, zea);  zeb = __fmaf_rn(zv[3], b0.w, zeb);
        zea = __fmaf_rn(zv[4], a1.x, zea);  zeb = __fmaf_rn(zv[4], b1.x, zeb);
        zea = __fmaf_rn(zv[5], a1.y, zea);  zeb = __fmaf_rn(zv[5], b1.y, zeb);
        zea = __fmaf_rn(zv[6], a1.z, zea);  zeb = __fmaf_rn(zv[6], b1.z, zeb);
        zea = __fmaf_rn(zv[7], a1.w, zea);  zeb = __fmaf_rn(zv[7], b1.w, zeb);

        const float ta = __fadd_rn(z2, ee.x);        // np: z2 + e2
        const float tb = __fadd_rn(z2, ee.y);
        const float da = __fmaf_rn(-2.0f, zea, ta);  // np: t - 2*ze (2*ze exact)
        const float db = __fmaf_rn(-2.0f, zeb, tb);

        const float vmin = fminf(da, db);
        // strict <: first pair achieving the global min wins (np first-min);
        // earlier pairs are all strictly greater (else np min would be earlier).
        if (vmin < dm) { dm = vmin; gbest = g; }
    }

    // exact within-pair resolution: recompute both dists with the identical
    // rounding chain; odd wins only if strictly less (np even-then-odd order).
    const float* ra = cb + (size_t)(2 * gbest) * DDIM;
    float zee = 0.0f, zeo = 0.0f;
    #pragma unroll
    for (int j = 0; j < DDIM; ++j) {
        zee = __fmaf_rn(zv[j], ra[j], zee);
        zeo = __fmaf_rn(zv[j], ra[DDIM + j], zeo);
    }
    const float de = __fmaf_rn(-2.0f, zee, __fadd_rn(z2, e2tab[2 * gbest]));
    const float dq = __fmaf_rn(-2.0f, zeo, __fadd_rn(z2, e2tab[2 * gbest + 1]));
    const int idx = (dq < de) ? (2 * gbest + 1) : (2 * gbest);

    out_idx[n] = (float)idx;

    const float* cw = cb + (size_t)idx * DDIM;
    float* op = out_zq + (size_t)b * B_STRIDE + s;
    float lsum = 0.0f;
    #pragma unroll
    for (int j = 0; j < DDIM; ++j) {
        const float zq = cw[j];
        const float t  = __fsub_rn(zq, zv[j]);           // np: z_q - z
        op[(size_t)j * CH_STRIDE] = __fadd_rn(zv[j], t); // np: z + (z_q - z)
        lsum = __fmaf_rn(t, t, lsum);                    // loss (2% tol)
    }

    // block reduction of loss partials: wave shuffle -> LDS -> one atomic/block
    #pragma unroll
    for (int off = 32; off > 0; off >>= 1) lsum += __shfl_down(lsum, off, 64);
    __shared__ float wsum[4];
    const int lane = threadIdx.x & 63;
    const int wid  = threadIdx.x >> 6;
    if (lane == 0) wsum[wid] = lsum;
    __syncthreads();
    if (threadIdx.x == 0) {
        float bs = ((wsum[0] + wsum[1]) + (wsum[2] + wsum[3]));
        // vq_loss = codebk + BETA*commit = 1.25 * mean((z_q - z)^2)
        atomicAdd(out_loss, bs * (1.25f / 4194304.0f));
    }
}

extern "C" void kernel_launch(void* const* d_in, const int* in_sizes, int n_in,
                              void* d_out, int out_size, void* d_ws, size_t ws_size,
                              hipStream_t stream) {
    const float* z  = (const float*)d_in[0];
    const float* cb = (const float*)d_in[1];
    float* out      = (float*)d_out;
    float* out_zq   = out;                    // 4194304 elems
    float* out_loss = out + 4194304;          // 1 elem
    float* out_idx  = out + 4194305;          // 524288 elems (as float values)
    float* e2       = (float*)d_ws;           // 512 floats

    prep_e2<<<1, 512, 0, stream>>>(cb, e2, out_loss);
    vq_main<<<NPTS / BLK, BLK, 0, stream>>>(z, cb, e2, out_zq, out_loss, out_idx);
}